// Round 9
// baseline (65.166 us; speedup 1.0000x reference)
//
#include <hip/hip_runtime.h>
#include <hip/hip_bf16.h>

// Problem constants (fixed by setup_inputs)
#define BATCH 4
#define NNODES 4096
#define HID 256
#define NHEADS 8
#define DH 32
#define DEG 16
#define NEDGES (BATCH * NNODES * DEG)   // 262144
#define NROWS (BATCH * NNODES)          // 16384 node-rows

typedef __attribute__((ext_vector_type(8))) short short8;
typedef __attribute__((ext_vector_type(8))) unsigned short ushort8;
typedef __attribute__((ext_vector_type(4))) unsigned short u16x4;  // 'ushort4' collides with HIP types
typedef __attribute__((ext_vector_type(4))) float f32x4;

static __device__ __forceinline__ unsigned short f2bf(float f) {
  __hip_bfloat16 h = __float2bfloat16(f);  // RNE
  return *reinterpret_cast<unsigned short*>(&h);
}
static __device__ __forceinline__ float bf2f(unsigned short u) {
  unsigned int v = ((unsigned int)u) << 16;
  return *reinterpret_cast<float*>(&v);
}

// ---------------------------------------------------------------------------
// Prep: X -> bf16 row-major Xb (blocks [0,2048)); Wt fragment-ordered bf16
// (96 blocks):
//   Wt[(mat*4+strip)*16384 + kk*2048 + hi*512 + col*8 + j]
//     = bf16( W_mat[kk*32 + hi*8 + j][strip*64 + col] )
// BW-bound (~5 us); moves all transpose/convert work out of the GEMM.
// ---------------------------------------------------------------------------
#define XBLOCKS 2048
#define WBLOCKS 96
__global__ __launch_bounds__(256) void prep_kernel(
    const float* __restrict__ X,
    const float* __restrict__ Wq, const float* __restrict__ Wk,
    const float* __restrict__ Wv,
    unsigned short* __restrict__ Xb, unsigned short* __restrict__ Wt) {
  const int tid = threadIdx.x;
  if (blockIdx.x < XBLOCKS) {
    const size_t base = (size_t)blockIdx.x * 2048 + (size_t)tid * 8;
    const float4 a = *reinterpret_cast<const float4*>(&X[base]);
    const float4 b = *reinterpret_cast<const float4*>(&X[base + 4]);
    ushort8 o;
    o[0] = f2bf(a.x); o[1] = f2bf(a.y); o[2] = f2bf(a.z); o[3] = f2bf(a.w);
    o[4] = f2bf(b.x); o[5] = f2bf(b.y); o[6] = f2bf(b.z); o[7] = f2bf(b.w);
    *reinterpret_cast<ushort8*>(&Xb[base]) = o;
  } else {
    const int o = (blockIdx.x - XBLOCKS) * 2048 + tid * 8;  // [0, 196608)
    const int mat   = o >> 16;
    const int w     = o & 65535;
    const int strip = w >> 14;
    const int r     = w & 16383;
    const int kk    = r >> 11;
    const int hi    = (r >> 9) & 3;
    const int col   = (r >> 3) & 63;
    const int k0    = kk * 32 + hi * 8;
    const int c     = strip * 64 + col;
    const float* __restrict__ W = (mat == 0) ? Wq : (mat == 1) ? Wk : Wv;
    ushort8 ovec;
    #pragma unroll
    for (int j = 0; j < 8; ++j) {
      ovec[j] = f2bf(W[(size_t)(k0 + j) * HID + c]);
    }
    *reinterpret_cast<ushort8*>(&Wt[o]) = ovec;
  }
}

// ---------------------------------------------------------------------------
// QKV projection, register-only (NO LDS, NO barriers). 1024 blocks = 4/CU,
// all co-resident (no LDS; launch_bounds(256,4) caps VGPR at 128).
//   xcd = bx&7, l = bx>>3: cs = l&3 (cols [cs*64,+64)),
//   chunk = (l>>2)*8 + xcd (64 rows, XCD-local so X rows stay L2-hot).
// Per wave: 8 A-frag loads (bf16 Xb, loaded ONCE, reused 12x), then
// 3 mats x 4 nt-tiles: 8 B-frag loads straight from L2-resident Wt
// (consumed immediately by 8 MFMAs -> no long-lived B registers, unlike R3)
// + bias + one vector store. Pure stream, latency hidden by TLP/ILP.
// MFMA operands swapped: mfma(Bf, Af) -> lane&15 = X-row, hi*4+reg = 4
// consecutive W-cols -> float4 (Q) / packed bf16x4 (K,V) stores.
// ---------------------------------------------------------------------------
__global__ __launch_bounds__(256, 4) void qkv_mfma_kernel(
    const unsigned short* __restrict__ Xb, const unsigned short* __restrict__ Wt,
    const float* __restrict__ bq, const float* __restrict__ bk,
    const float* __restrict__ bv,
    float* __restrict__ Qs, unsigned short* __restrict__ Kb,
    unsigned short* __restrict__ Vb) {
  const int tid = threadIdx.x;
  const int xcd = blockIdx.x & 7;
  const int l = blockIdx.x >> 3;        // 0..127
  const int cs = l & 3;                 // col-strip
  const int chunk = (l >> 2) * 8 + xcd; // 0..255, XCD-local
  const int c0 = cs * 64;

  const int lane = tid & 63;
  const int wv = tid >> 6;
  const int lm = lane & 15;
  const int hi = lane >> 4;             // 0..3
  const int lk = hi * 8;
  const int row = chunk * 64 + wv * 16 + lm;

  // A-fragments (bf16), loaded once, reused for all 12 output tiles.
  short8 Af[8];
  #pragma unroll
  for (int kk = 0; kk < 8; ++kk) {
    Af[kk] = *reinterpret_cast<const short8*>(
        &Xb[(size_t)row * 256 + kk * 32 + lk]);
  }

  #pragma unroll
  for (int m = 0; m < 3; ++m) {
    const unsigned short* __restrict__ Wm = Wt + (size_t)(m * 4 + cs) * 16384;
    const float* __restrict__ bias = (m == 0) ? bq : (m == 1) ? bk : bv;

    #pragma unroll
    for (int nt = 0; nt < 4; ++nt) {
      short8 Bf[8];
      #pragma unroll
      for (int kk = 0; kk < 8; ++kk) {
        Bf[kk] = *reinterpret_cast<const short8*>(
            &Wm[kk * 2048 + hi * 512 + (nt * 16 + lm) * 8]);
      }
      f32x4 acc = {0.f, 0.f, 0.f, 0.f};
      #pragma unroll
      for (int kk = 0; kk < 8; ++kk) {
        acc = __builtin_amdgcn_mfma_f32_16x16x32_bf16(Bf[kk], Af[kk], acc, 0, 0, 0);
      }
      const int col0 = c0 + nt * 16 + hi * 4;
      const float4 b4 = *reinterpret_cast<const float4*>(&bias[col0]);
      if (m == 0) {
        float4 o;
        o.x = acc[0] + b4.x; o.y = acc[1] + b4.y;
        o.z = acc[2] + b4.z; o.w = acc[3] + b4.w;
        *reinterpret_cast<float4*>(&Qs[(size_t)row * 256 + col0]) = o;
      } else {
        u16x4 o;
        o[0] = f2bf(acc[0] + b4.x); o[1] = f2bf(acc[1] + b4.y);
        o[2] = f2bf(acc[2] + b4.z); o[3] = f2bf(acc[3] + b4.w);
        unsigned short* __restrict__ dst = (m == 1) ? Kb : Vb;
        *reinterpret_cast<u16x4*>(&dst[(size_t)row * 256 + col0]) = o;
      }
    }
  }
}

// ---------------------------------------------------------------------------
// Attention. One block per segment, 256 threads = 4 waves; wave wv owns
// heads {2wv, 2wv+1} in BOTH phases (phase-3 channels [wv*64,+64) -> heads
// 2wv/2wv+1), so the s_w handoff is wave-local: no __syncthreads needed,
// just an LDS fence (s_waitcnt lgkmcnt(0)).
// Lane map: lane = j*4 + hh*2 + p. In-wave softmax over j (lane bits 2..5).
// XCD swizzle: each XCD works one batch -> K/V L2 locality.
// ---------------------------------------------------------------------------
__global__ __launch_bounds__(256) void attn_kernel(
    const float* __restrict__ Q, const unsigned short* __restrict__ K,
    const unsigned short* __restrict__ V, const int* __restrict__ edges,
    float* __restrict__ out) {
  __shared__ float s_w[DEG * NHEADS];   // [j][h], 512 B

  const int bx = blockIdx.x;
  const int xcd = bx & 7;
  const int g = (xcd >> 1) * NNODES + (((bx >> 3) << 1) | (xcd & 1));
  const int e0 = g * DEG;
  const int tid = threadIdx.x;

  const int b = edges[e0];                            // block-uniform
  const int qrow = b * NNODES + edges[NEDGES + e0];   // block-uniform

  // ---- Phase 1 + in-wave softmax ----
  const int lane = tid & 63;
  const int wv = tid >> 6;
  const int j = lane >> 2;
  const int hh = (lane >> 1) & 1;
  const int p = lane & 1;
  const int h = wv * 2 + hh;
  const int ch0 = h * 32 + p * 16;

  const int nsrc = b * NNODES + edges[2 * NEDGES + e0 + j];  // 16 distinct, coalesced

  const float* __restrict__ qp = &Q[(size_t)qrow * HID + ch0];
  const float4 q0 = *reinterpret_cast<const float4*>(qp);
  const float4 q1 = *reinterpret_cast<const float4*>(qp + 4);
  const float4 q2 = *reinterpret_cast<const float4*>(qp + 8);
  const float4 q3 = *reinterpret_cast<const float4*>(qp + 12);
  const unsigned short* __restrict__ kp = &K[(size_t)nsrc * HID + ch0];
  const ushort8 k0 = *reinterpret_cast<const ushort8*>(kp);
  const ushort8 k1 = *reinterpret_cast<const ushort8*>(kp + 8);

  float partial;
  partial  = q0.x * bf2f(k0[0]); partial = fmaf(q0.y, bf2f(k0[1]), partial);
  partial = fmaf(q0.z, bf2f(k0[2]), partial); partial = fmaf(q0.w, bf2f(k0[3]), partial);
  partial = fmaf(q1.x, bf2f(k0[4]), partial); partial = fmaf(q1.y, bf2f(k0[5]), partial);
  partial = fmaf(q1.z, bf2f(k0[6]), partial); partial = fmaf(q1.w, bf2f(k0[7]), partial);
  partial = fmaf(q2.x, bf2f(k1[0]), partial); partial = fmaf(q2.y, bf2f(k1[1]), partial);
  partial = fmaf(q2.z, bf2f(k1[2]), partial); partial = fmaf(q2.w, bf2f(k1[3]), partial);
  partial = fmaf(q3.x, bf2f(k1[4]), partial); partial = fmaf(q3.y, bf2f(k1[5]), partial);
  partial = fmaf(q3.z, bf2f(k1[6]), partial); partial = fmaf(q3.w, bf2f(k1[7]), partial);

  partial += __shfl_xor(partial, 1);                 // combine p-halves
  const float sc = partial * 0.17677669529663687f;   // 1/sqrt(DH)

  float mx = sc;                                     // reduce over j (lane bits 2..5)
  mx = fmaxf(mx, __shfl_xor(mx, 4));
  mx = fmaxf(mx, __shfl_xor(mx, 8));
  mx = fmaxf(mx, __shfl_xor(mx, 16));
  mx = fmaxf(mx, __shfl_xor(mx, 32));
  const float e = __expf(sc - mx);
  float sum = e;
  sum += __shfl_xor(sum, 4);
  sum += __shfl_xor(sum, 8);
  sum += __shfl_xor(sum, 16);
  sum += __shfl_xor(sum, 32);

  if (p == 0) s_w[j * NHEADS + h] = e / sum;
  // Wave-local handoff: fence LDS, no all-wave barrier needed.
  asm volatile("s_waitcnt lgkmcnt(0)" ::: "memory");

  // ---- Phase 3: weighted V gather-sum (tid = channel) ----
  const int h3 = tid >> 5;
  float acc = 0.0f;
  #pragma unroll
  for (int jj = 0; jj < DEG; ++jj) {
    const int n = b * NNODES + edges[2 * NEDGES + e0 + jj];  // uniform scalar loads
    acc = fmaf(s_w[jj * NHEADS + h3], bf2f(V[(size_t)n * HID + tid]), acc);
  }
  out[(size_t)qrow * HID + tid] = acc;
}

// ---------------------------------------------------------------------------
extern "C" void kernel_launch(void* const* d_in, const int* in_sizes, int n_in,
                              void* d_out, int out_size, void* d_ws, size_t ws_size,
                              hipStream_t stream) {
  const float* X     = (const float*)d_in[0];
  const int*   edges = (const int*)d_in[1];
  const float* Wq    = (const float*)d_in[2];
  const float* bq    = (const float*)d_in[3];
  const float* Wk    = (const float*)d_in[4];
  const float* bk    = (const float*)d_in[5];
  const float* Wv    = (const float*)d_in[6];
  const float* bv    = (const float*)d_in[7];
  float* out = (float*)d_out;

  // Workspace: Qs fp32 16MiB | Kb bf16 8MiB | Vb bf16 8MiB | Xb bf16 8MiB |
  //            Wt bf16 384KiB  (~40.4 MiB total)
  char* w = (char*)d_ws;
  float*          Qs = (float*)w;                 w += (size_t)NROWS * HID * 4;
  unsigned short* Kb = (unsigned short*)w;        w += (size_t)NROWS * HID * 2;
  unsigned short* Vb = (unsigned short*)w;        w += (size_t)NROWS * HID * 2;
  unsigned short* Xb = (unsigned short*)w;        w += (size_t)NROWS * HID * 2;
  unsigned short* Wt = (unsigned short*)w;

  prep_kernel<<<XBLOCKS + WBLOCKS, 256, 0, stream>>>(X, Wq, Wk, Wv, Xb, Wt);
  qkv_mfma_kernel<<<1024, 256, 0, stream>>>(Xb, Wt, bq, bk, bv, Qs, Kb, Vb);
  attn_kernel<<<NROWS, 256, 0, stream>>>(Qs, Kb, Vb, edges, out);
}